// Round 7
// baseline (594.397 us; speedup 1.0000x reference)
//
#include <hip/hip_runtime.h>
#include <math.h>

// SSDLite post-processing, round 14: single-wave-per-class, fully resident.
// Round-13 post-mortem: inverted probe REVERTED (serial ctz/readlane/ballot
// chain per candidate, no ILP -> slower despite fewer wave-instr).
// Rounds 11/12/13 all sit at VALUBusy ~66-67% with makespan = W*2cyc/(4*busy)
// -> issue-capacity-bound with a structural idle: 20 class-units/CU x 2
// waves = 40 waves > 32 HW max, so the cooperative grid ALWAYS runs a
// 16-then-4 two-round schedule (measured Occ 66% = (100+25)/2), tail at 1/4
// occupancy = the ~20% slack.
// Fix: schedulable unit = 1 wave = 1 class (round-7 skeleton) with round-12's
// lean body: grid = batch*10, 128-thr blocks of 2 INDEPENDENT class-waves,
// 14.7 KB LDS -> 10 blocks/CU = 20 waves/CU, all co-resident in ONE round,
// ZERO barriers (same-wave DS in-order). Per-class latency doubles but
// latency is free when everything is resident and issue-bound.
// Kept from round 12: float-max suppression accumulator (m>0 <=> suppressed,
// exactly OR-of-predicates), karr ds_read_b128, XCD swizzle (image's 10
// blocks on one XCD's L2), re-read compaction (no sb[] spill), exact 2x-fma
// IoU predicate + reference decode op order => identical kept sequence.

#define NCLS 21
#define TOPK 200
#define NPRI 3000
#define ELTS 47            // ceil(3000/64)
#define CONF_T 0.01f
#define MHI 0.45f
#define MLO 1.490116119384765625e-08f   // 2^-26 == ulp(0.45f)/2
#define CAP 256            // sort/batch capacity
#define NBUCK 256          // histogram buckets (224 used)
#define NUSED 224
#define BITS_BASE 0x3C000000u           // bits(2^-7); 0.01 > 2^-7
#define BSHIFT 18

__device__ __forceinline__ float rdlf(float v, int l) {
  return __int_as_float(__builtin_amdgcn_readlane(__float_as_int(v), l));
}

// IoU suppression VALUE: >0 means suppressed. EXACT reference numerics
// (2x fma, MLO half-ulp nudge) -- same expression as all passing rounds.
__device__ __forceinline__ float iou_val(const float4 k, const float a,
                                         const float4 b, const float carea) {
  float ltx = fmaxf(k.x, b.x), lty = fmaxf(k.y, b.y);
  float rbx = fminf(k.z, b.z), rby = fminf(k.w, b.w);
  float iw = fmaxf(rbx - ltx, 0.0f), ih = fmaxf(rby - lty, 0.0f);
  float inter = iw * ih;
  float uni = (a + carea) - inter;
  return fmaf(-MLO, uni, fmaf(-MHI, uni, inter));
}

// Serial keep-resolution of one wave's tile. All lanes return the same nk.
__device__ __forceinline__ int resolve_tile(
    unsigned long long smask, const float4 bx, const float carea,
    const unsigned int bits, const int lane, int nk,
    float4* kbox, float* karr, float* kscore) {
  unsigned long long M = ~smask;
  int nCnt = 0;                       // boxes kept since tile start
  float nx1 = 0, ny1 = 0, nx2 = 0, ny2 = 0, nar = 0;  // lane t = new #t
  while (M && nk < TOPK) {
    int ls = (int)__builtin_ctzll(M);
    M &= M - 1ull;
    float sx1 = rdlf(bx.x, ls), sy1 = rdlf(bx.y, ls);
    float sx2 = rdlf(bx.z, ls), sy2 = rdlf(bx.w, ls);
    float sar = rdlf(carea, ls);
    unsigned int sbits =
        (unsigned int)__builtin_amdgcn_readlane((int)bits, ls);

    bool s_sup = false;
    if (lane < nCnt) {
      float ltx = fmaxf(nx1, sx1), lty = fmaxf(ny1, sy1);
      float rbx = fminf(nx2, sx2), rby = fminf(ny2, sy2);
      float iw = fmaxf(rbx - ltx, 0.0f), ih = fmaxf(rby - lty, 0.0f);
      float inter = iw * ih;
      float uni = (nar + sar) - inter;
      s_sup = fmaf(-MLO, uni, fmaf(-MHI, uni, inter)) > 0.0f;
    }
    if (__ballot(s_sup) != 0ull) continue;   // suppressed, not kept

    if (lane == nCnt) { nx1 = sx1; ny1 = sy1; nx2 = sx2; ny2 = sy2; nar = sar; }
    if (lane == 0) {
      kbox[nk]   = make_float4(sx1, sy1, sx2, sy2);
      karr[nk]   = sar;
      kscore[nk] = __uint_as_float(sbits);
    }
    ++nCnt;
    ++nk;
  }
  return nk;
}

__global__ void decode_kernel(const float* __restrict__ loc,
                              const float* __restrict__ priors,
                              float4* __restrict__ wsbox,
                              float* __restrict__ out) {
  const int b = blockIdx.x;
  // class-0 rows are all zeros
  float* o0 = out + (size_t)b * NCLS * TOPK * 5;
  for (int i = threadIdx.x; i < TOPK * 5; i += 256) o0[i] = 0.0f;
  for (int j = threadIdx.x; j < NPRI; j += 256) {
    const float4 l4 = *(const float4*)(loc + ((size_t)b * NPRI + j) * 4);
    const float4 p  = *(const float4*)(priors + (size_t)j * 4);
    float cx = p.x + (l4.x * 0.1f) * p.z;
    float cy = p.y + (l4.y * 0.1f) * p.w;
    float bw = p.z * expf(l4.z * 0.2f);
    float bh = p.w * expf(l4.w * 0.2f);
    wsbox[(size_t)b * NPRI + j] = make_float4(cx - bw * 0.5f, cy - bh * 0.5f,
                                              cx + bw * 0.5f, cy + bh * 0.5f);
  }
}

__global__ __launch_bounds__(128, 5) void ssd_nms_kernel(
    const float* __restrict__ conf, const float4* __restrict__ wsbox,
    float* __restrict__ out, int nbatch) {
  const int blk = blockIdx.x;
  int b, g;
  if ((nbatch & 7) == 0) {
    // XCD swizzle: image b's 10 blocks all land on XCD b&7 -> the image's
    // conf slab + wsbox stay in one XCD's L2.
    const int xcd  = blk & 7;
    const int rest = blk >> 3;
    b = (rest / 10) * 8 + xcd;
    g = rest % 10;
  } else {
    b = blk / 10;
    g = blk % 10;
  }
  const int tid  = threadIdx.x;
  const int lane = tid & 63;
  const int w    = tid >> 6;          // wave in block (2 independent classes)
  const int c    = 1 + g * 2 + w;     // class in [1,20]

  __shared__ unsigned long long skey[2][CAP];    // 4,096 B sort bufs
  __shared__ unsigned int hist[2][NBUCK / 2];    // 1,024 B packed u16 hists
  __shared__ float4 kbox[2][TOPK];               // 6,400 B kept boxes
  __shared__ alignas(16) float karr[2][TOPK];    // 1,600 B kept areas
  __shared__ float  kscore[2][TOPK];             // 1,600 B kept scores
  // total 14,720 B -> 10 blocks/CU (20 waves, all resident, one round)

  for (int i = lane; i < NBUCK / 2; i += 64) hist[w][i] = 0u;

  const float* myF = conf + (size_t)b * NPRI * NCLS + c;

  // ---- per-wave histogram over thresholded score bits ----
#pragma unroll 4
  for (int k = 0; k < ELTS; ++k) {
    const int j = k * 64 + lane;
    unsigned int bits = 0u;
    if (j < NPRI) {
      float s = myF[(size_t)j * NCLS];
      bits = (s > CONF_T) ? __float_as_uint(s) : 0u;
    }
    if (bits) {
      unsigned int bu = (bits - BITS_BASE) >> BSHIFT;   // 8..223
      atomicAdd(&hist[w][bu >> 1], 1u << ((bu & 1) * 16));
    }
  }
  // same-wave DS ops are in-order: no barriers anywhere in this kernel

  float* obase = out + ((size_t)b * NCLS + c) * (TOPK * 5);
  const float4* mybox = wsbox + (size_t)b * NPRI;
  int nk = 0;
  int cutHiB = NUSED;

  while (nk < TOPK && cutHiB > 0) {
    // ---- pick batch: largest 4-bucket-granular suffix with count<=CAP ----
    int sl = 0;
#pragma unroll
    for (int t = 0; t < 4; ++t) {
      int bu = lane * 4 + t;
      if (bu < cutHiB) sl += (int)((hist[w][bu >> 1] >> ((bu & 1) * 16)) & 0xFFFFu);
    }
    int suf = sl;
#pragma unroll
    for (int d = 1; d < 64; d <<= 1) {
      int v = __shfl_down(suf, d, 64);
      if (lane + d < 64) suf += v;
    }
    unsigned long long m = __ballot(suf <= CAP);
    int Ls = (m != 0ull) ? __builtin_ctzll(m) : 63;
    int cutLoB = Ls * 4;
    if (cutLoB >= cutHiB) cutLoB = (cutHiB - 1) & ~3;   // degenerate, P~0
    const unsigned int loBits = BITS_BASE + ((unsigned)cutLoB << BSHIFT);
    const unsigned int hiBits = BITS_BASE + ((unsigned)cutHiB << BSHIFT);

    // ---- compact batch members (ballot prefix, running base) ----
#pragma unroll
    for (int t = 0; t < CAP / 64; ++t) skey[w][t * 64 + lane] = 0ull;
    int base = 0;
#pragma unroll 2
    for (int k = 0; k < ELTS; ++k) {
      const int j = k * 64 + lane;
      unsigned int bits = 0u;
      if (j < NPRI) {
        float s = myF[(size_t)j * NCLS];
        bits = (s > CONF_T) ? __float_as_uint(s) : 0u;
      }
      bool sel = (bits >= loBits) && (bits < hiBits);
      unsigned long long bm = __ballot(sel);
      if (sel) {
        int pos = base + (int)__popcll(bm & ((1ull << lane) - 1ull));
        if (pos < CAP)
          skey[w][pos] = ((unsigned long long)bits << 12) | (unsigned)(4095 - j);
      }
      base += (int)__popcll(bm);
    }
    int Nc = (base > CAP) ? CAP : base;

    if (Nc > 0) {
      // ---- bitonic sort descending, u64 keys, wave-synchronous ----
      unsigned long long* sk = &skey[w][0];
      for (int kk = 2; kk <= CAP; kk <<= 1) {
        for (int jj = kk >> 1; jj > 0; jj >>= 1) {
#pragma unroll
          for (int t = 0; t < CAP / 64; ++t) {
            int i = t * 64 + lane;
            int ixj = i ^ jj;
            if (ixj > i) {
              unsigned long long a = sk[i], d = sk[ixj];
              bool up = (i & kk) == 0;
              bool swp = up ? (a < d) : (a > d);
              if (swp) { sk[i] = d; sk[ixj] = a; }
            }
          }
          __threadfence_block();
        }
      }

      // ---- tile scan: 64 sorted candidates at a time ----
      for (int p0 = 0; p0 < Nc && nk < TOPK; p0 += 64) {
        const int p = p0 + lane;
        const bool valid = p < Nc;
        unsigned long long key = valid ? sk[p] : 0ull;
        unsigned int bits = (unsigned int)(key >> 12);
        int j = 4095 - (int)(key & 4095ull);
        float4 bx = mybox[valid ? j : 0];
        float carea = (bx.z - bx.x) * (bx.w - bx.y);

        // dense vs kept[0..nk): float-max suppression accumulator
        // (m>0 <=> suppressed; exactly OR of per-kept predicates).
        float fm = valid ? -1.0f : 1.0f;   // padding pre-suppressed
        int s = 0;
        for (; s + 3 < nk; s += 4) {
          float4 k0 = kbox[w][s];     float4 k1 = kbox[w][s + 1];
          float4 k2 = kbox[w][s + 2]; float4 k3 = kbox[w][s + 3];
          float4 ar = *(const float4*)&karr[w][s];   // one ds_read_b128
          float v01 = fmaxf(iou_val(k0, ar.x, bx, carea),
                            iou_val(k1, ar.y, bx, carea));
          float v23 = fmaxf(iou_val(k2, ar.z, bx, carea),
                            iou_val(k3, ar.w, bx, carea));
          fm = fmaxf(fm, fmaxf(v01, v23));
          if (__ballot(fm > 0.0f) == ~0ull) { s = nk; break; }
        }
        for (; s < nk; ++s)
          fm = fmaxf(fm, iou_val(kbox[w][s], karr[w][s], bx, carea));
        unsigned long long smask = __ballot(fm > 0.0f);

        nk = resolve_tile(smask, bx, carea, bits, lane, nk,
                          &kbox[w][0], &karr[w][0], &kscore[w][0]);
      }
    }
    cutHiB = cutLoB;
  }

  // ---- coalesced output dump: rows (score,x1,y1,x2,y2), zeros past nk ----
  const float* kbf = (const float*)&kbox[w][0];
  for (int i = lane; i < TOPK * 5; i += 64) {
    int r = i / 5;
    int col = i - r * 5;
    float v = 0.0f;
    if (r < nk) v = (col == 0) ? kscore[w][r] : kbf[r * 4 + (col - 1)];
    obase[i] = v;
  }
}

extern "C" void kernel_launch(void* const* d_in, const int* in_sizes, int n_in,
                              void* d_out, int out_size, void* d_ws, size_t ws_size,
                              hipStream_t stream) {
  const float* loc    = (const float*)d_in[0];
  const float* conf   = (const float*)d_in[1];
  const float* priors = (const float*)d_in[2];
  float* out = (float*)d_out;
  float4* wsbox = (float4*)d_ws;      // batch*3000*16 B = 12.3 MB

  const int batch = in_sizes[0] / (NPRI * 4);
  hipLaunchKernelGGL(decode_kernel, dim3(batch), dim3(256), 0, stream,
                     loc, priors, wsbox, out);
  hipLaunchKernelGGL(ssd_nms_kernel, dim3(batch * 10), dim3(128), 0, stream,
                     conf, wsbox, out, batch);
}

// Round 8
// 430.899 us; speedup vs baseline: 1.3794x; 1.3794x over previous
//
#include <hip/hip_runtime.h>
#include <math.h>

// SSDLite post-processing, round 15 = round 12 (388us nms, best known) with
// the serial resolve loop rewritten as an M-refilter. Round-14 post-mortem:
// single-wave residency REVERTED (20 waves/CU -> busy 45.6% vs round 12's
// 32-wave phase-1 at 67%; occupancy ledger corrected: launch_bounds(128,8)
// = 16 blocks x 2 waves = 32 waves/CU).
// M-refilter resolve: pop lowest surviving lane (mask-filtered => guaranteed
// keepable), broadcast its box, ALL lanes test their own candidate against
// it in parallel, M &= ~ballot(hit). Rejected survivors cost ZERO loop
// iterations (old: full ctz+5 readlane+staged-news test per event, ~3 events
// per kept). Bit-exact: same iou_val orientation (kept area first in uni),
// fp add/fmax commutative bitwise, pop order = sequential scan order.
// Everything else byte-identical to round 12: 2-wave coop class blocks
// (grid=batch*20, 128 thr, 7.4KB LDS, 16 blocks/CU), XCD swizzle, float-max
// dense accumulator, karr ds_read_b128, 2-barrier bitonic sort + post-sort
// barrier, tile-pair scan, exact 2x-fma IoU predicate.

#define NCLS 21
#define TOPK 200
#define NPRI 3000
#define ELTS 47            // ceil(3000/64)
#define CONF_T 0.01f
#define MHI 0.45f
#define MLO 1.490116119384765625e-08f   // 2^-26 == ulp(0.45f)/2
#define CAP 256            // sort/batch capacity
#define NBUCK 256          // histogram buckets (224 used)
#define NUSED 224
#define BITS_BASE 0x3C000000u           // bits(2^-7); 0.01 > 2^-7
#define BSHIFT 18

__device__ __forceinline__ float rdlf(float v, int l) {
  return __int_as_float(__builtin_amdgcn_readlane(__float_as_int(v), l));
}

// IoU suppression VALUE: >0 means suppressed. EXACT reference numerics
// (2x fma, MLO half-ulp nudge) -- same expression as all passing rounds.
// Symmetric in the box pair; 'a' = kept-box area everywhere (uni add order).
__device__ __forceinline__ float iou_val(const float4 k, const float a,
                                         const float4 b, const float carea) {
  float ltx = fmaxf(k.x, b.x), lty = fmaxf(k.y, b.y);
  float rbx = fminf(k.z, b.z), rby = fminf(k.w, b.w);
  float iw = fmaxf(rbx - ltx, 0.0f), ih = fmaxf(rby - lty, 0.0f);
  float inter = iw * ih;
  float uni = (a + carea) - inter;
  return fmaf(-MLO, uni, fmaf(-MHI, uni, inter));
}

__device__ __forceinline__ bool iou_sup(const float4 k, const float a,
                                        const float4 b, const float carea) {
  return iou_val(k, a, b, carea) > 0.0f;
}

// M-refilter keep-resolution. M starts as the dense-survivor mask; popping
// the lowest set lane yields a box unsuppressed by all olds (dense) and all
// news (filtered) -> kept. Then one parallel iou of every lane's candidate
// vs the new box prunes M. Identical kept sequence to the sequential scan.
__device__ __forceinline__ int resolve_tile(
    unsigned long long smask, const float4 bx, const float carea,
    const unsigned int bits, const int lane, int nk,
    float4* kbox, float* karr, float* kscore) {
  unsigned long long M = ~smask;
  while (M && nk < TOPK) {
    const int ls = (int)__builtin_ctzll(M);
    const float sx1 = rdlf(bx.x, ls), sy1 = rdlf(bx.y, ls);
    const float sx2 = rdlf(bx.z, ls), sy2 = rdlf(bx.w, ls);
    const float sar = rdlf(carea, ls);
    const unsigned int sbits =
        (unsigned int)__builtin_amdgcn_readlane((int)bits, ls);
    const float4 nb = make_float4(sx1, sy1, sx2, sy2);
    if (lane == 0) {
      kbox[nk]   = nb;
      karr[nk]   = sar;
      kscore[nk] = __uint_as_float(sbits);
    }
    ++nk;
    // prune remaining survivors by the newly kept box (self included: iou=1)
    M &= ~__ballot(iou_val(nb, sar, bx, carea) > 0.0f);
    M &= ~(1ull << ls);
  }
  return nk;
}

__global__ void decode_kernel(const float* __restrict__ loc,
                              const float* __restrict__ priors,
                              float4* __restrict__ wsbox,
                              float* __restrict__ out) {
  const int b = blockIdx.x;
  // class-0 rows are all zeros
  float* o0 = out + (size_t)b * NCLS * TOPK * 5;
  for (int i = threadIdx.x; i < TOPK * 5; i += 256) o0[i] = 0.0f;
  for (int j = threadIdx.x; j < NPRI; j += 256) {
    const float4 l4 = *(const float4*)(loc + ((size_t)b * NPRI + j) * 4);
    const float4 p  = *(const float4*)(priors + (size_t)j * 4);
    float cx = p.x + (l4.x * 0.1f) * p.z;
    float cy = p.y + (l4.y * 0.1f) * p.w;
    float bw = p.z * expf(l4.z * 0.2f);
    float bh = p.w * expf(l4.w * 0.2f);
    wsbox[(size_t)b * NPRI + j] = make_float4(cx - bw * 0.5f, cy - bh * 0.5f,
                                              cx + bw * 0.5f, cy + bh * 0.5f);
  }
}

__global__ __launch_bounds__(128, 8) void ssd_nms_kernel(
    const float* __restrict__ conf, const float4* __restrict__ wsbox,
    float* __restrict__ out, int nbatch) {
  const int blk = blockIdx.x;
  int b, c1;
  if ((nbatch & 7) == 0) {
    // XCD swizzle: image b's 20 class-blocks land on XCD b&7 -> the image's
    // conf slab + wsbox stay in one XCD's L2.
    const int xcd  = blk & 7;
    const int rest = blk >> 3;
    b  = (rest / 20) * 8 + xcd;
    c1 = rest % 20;
  } else {
    b  = blk / 20;
    c1 = blk % 20;
  }
  const int c    = 1 + c1;            // class in [1,20]
  const int tid  = threadIdx.x;
  const int lane = tid & 63;
  const int w    = tid >> 6;          // wave in block (2 waves, one class)

  __shared__ unsigned long long skey[CAP];       // 2,048 B sort buf
  __shared__ unsigned int hist[NBUCK / 2];       //   512 B packed u16 hist
  __shared__ float4 kbox[TOPK];                  // 3,200 B kept boxes
  __shared__ alignas(16) float karr[TOPK];       //   800 B kept areas
  __shared__ float  kscore[TOPK];                //   800 B kept scores
  __shared__ int sh_nk;                          // block-consistent kept count
  __shared__ int sh_ctr;                         // compaction position counter

  for (int i = tid; i < NBUCK / 2; i += 128) hist[i] = 0u;
  if (tid == 0) sh_nk = 0;
  __syncthreads();

  const float* myF = conf + (size_t)b * NPRI * NCLS + c;

  // ---- histogram over thresholded score bits, j-space split by wave ----
  for (int k = w; k < ELTS; k += 2) {
    const int j = k * 64 + lane;
    unsigned int bits = 0u;
    if (j < NPRI) {
      float s = myF[(size_t)j * NCLS];
      bits = (s > CONF_T) ? __float_as_uint(s) : 0u;
    }
    if (bits) {
      unsigned int bu = (bits - BITS_BASE) >> BSHIFT;   // 8..223
      atomicAdd(&hist[bu >> 1], 1u << ((bu & 1) * 16));
    }
  }
  __syncthreads();

  float* obase = out + ((size_t)b * NCLS + c) * (TOPK * 5);
  const float4* mybox = wsbox + (size_t)b * NPRI;
  int cutHiB = NUSED;

  for (;;) {
    // round head: sh_nk last written before a barrier -> both waves agree
    if (sh_nk >= TOPK || cutHiB <= 0) break;

    // ---- pick batch (both waves redundantly, identical result) ----
    int sl = 0;
#pragma unroll
    for (int t = 0; t < 4; ++t) {
      int bu = lane * 4 + t;
      if (bu < cutHiB) sl += (int)((hist[bu >> 1] >> ((bu & 1) * 16)) & 0xFFFFu);
    }
    int suf = sl;
#pragma unroll
    for (int d = 1; d < 64; d <<= 1) {
      int v = __shfl_down(suf, d, 64);
      if (lane + d < 64) suf += v;
    }
    unsigned long long m = __ballot(suf <= CAP);
    int Ls = (m != 0ull) ? __builtin_ctzll(m) : 63;
    int cutLoB = Ls * 4;
    if (cutLoB >= cutHiB) cutLoB = (cutHiB - 1) & ~3;   // degenerate, P~0
    const unsigned int loBits = BITS_BASE + ((unsigned)cutLoB << BSHIFT);
    const unsigned int hiBits = BITS_BASE + ((unsigned)cutHiB << BSHIFT);

    // ---- compact batch members; position via shared atomic (order is
    //      irrelevant: keys unique, sort follows) ----
    if (tid == 0) sh_ctr = 0;
    for (int t = tid; t < CAP; t += 128) skey[t] = 0ull;
    __syncthreads();

    for (int k = w; k < ELTS; k += 2) {
      const int j = k * 64 + lane;
      unsigned int bits = 0u;
      if (j < NPRI) {
        float s = myF[(size_t)j * NCLS];
        bits = (s > CONF_T) ? __float_as_uint(s) : 0u;
      }
      bool sel = (bits >= loBits) && (bits < hiBits);
      unsigned long long bm = __ballot(sel);
      int cnt = (int)__popcll(bm);
      int wb = 0;
      if (lane == 0 && cnt) wb = atomicAdd(&sh_ctr, cnt);
      wb = __builtin_amdgcn_readfirstlane(wb);
      if (sel) {
        int pos = wb + (int)__popcll(bm & ((1ull << lane) - 1ull));
        if (pos < CAP)
          skey[pos] = ((unsigned long long)bits << 12) | (unsigned)(4095 - j);
      }
    }
    __syncthreads();
    int Nc = sh_ctr;
    if (Nc > CAP) Nc = CAP;

    if (Nc > 0) {
      // ---- bitonic sort descending, 128 threads, 1 pair/thread/pass.
      //      Mapping keeps jj<=64 passes inside one wave's half of skey;
      //      only jj=128 crosses waves -> 2 barriers mid-sort. ----
      for (int kk = 2; kk <= CAP; kk <<= 1) {
        for (int jj = kk >> 1; jj > 0; jj >>= 1) {
          if (jj == 128) __syncthreads();   // about to read across halves
          int i = ((tid & ~(jj - 1)) << 1) | (tid & (jj - 1));
          int ixj = i | jj;
          unsigned long long a = skey[i], d = skey[ixj];
          bool up = (i & kk) == 0;
          if (up ? (a < d) : (a > d)) { skey[i] = d; skey[ixj] = a; }
          if (jj == 128) __syncthreads();   // cross-half writes visible
          else __threadfence_block();       // same-wave DS in-order
        }
      }
      // scan reads skey across wave halves: make the sort's final intra-half
      // passes visible block-wide before any scan read (round-10 bug fix).
      __syncthreads();

      // ---- tile-pair scan: wave w dense-tests tile 2p+w vs the kept
      //      snapshot in parallel; serial resolution stays in order ----
      for (int p0 = 0;; p0 += 128) {
        if (p0 >= Nc) break;
        const int nk0 = sh_nk;            // post-barrier consistent snapshot
        if (nk0 >= TOPK) break;

        const int p = p0 + w * 64 + lane;
        const bool valid = p < Nc;
        unsigned long long key = valid ? skey[p] : 0ull;
        unsigned int bits = (unsigned int)(key >> 12);
        int j = 4095 - (int)(key & 4095ull);
        float4 bx = mybox[valid ? j : 0];
        float carea = (bx.z - bx.x) * (bx.w - bx.y);

        // dense vs kept[0..nk0): float-max suppression accumulator
        // (m>0 <=> suppressed; exactly OR of per-kept predicates).
        float fm = valid ? -1.0f : 1.0f;   // padding pre-suppressed
        int s = 0;
        for (; s + 3 < nk0; s += 4) {
          float4 k0 = kbox[s];     float4 k1 = kbox[s + 1];
          float4 k2 = kbox[s + 2]; float4 k3 = kbox[s + 3];
          float4 ar = *(const float4*)&karr[s];   // one ds_read_b128
          float v01 = fmaxf(iou_val(k0, ar.x, bx, carea),
                            iou_val(k1, ar.y, bx, carea));
          float v23 = fmaxf(iou_val(k2, ar.z, bx, carea),
                            iou_val(k3, ar.w, bx, carea));
          fm = fmaxf(fm, fmaxf(v01, v23));
          if (__ballot(fm > 0.0f) == ~0ull) { s = nk0; break; }
        }
        for (; s < nk0; ++s)
          fm = fmaxf(fm, iou_val(kbox[s], karr[s], bx, carea));
        unsigned long long smask = __ballot(fm > 0.0f);

        if (w == 0) {   // resolve tile 2p (writes kbox[nk0..), disjoint from
                        // wave 1's concurrent reads of kbox[0..nk0))
          int nk = resolve_tile(smask, bx, carea, bits, lane, nk0,
                                kbox, karr, kscore);
          if (lane == 0) sh_nk = nk;
        }
        __syncthreads();
        if (w == 1) {   // catch-up vs keeps added by tile 2p, then resolve
          const int nk1 = sh_nk;
          for (int s2 = nk0; s2 < nk1; ++s2) {
            smask |= __ballot(iou_sup(kbox[s2], karr[s2], bx, carea));
            if (smask == ~0ull) break;
          }
          int nk = resolve_tile(smask, bx, carea, bits, lane, nk1,
                                kbox, karr, kscore);
          if (lane == 0) sh_nk = nk;
        }
        __syncthreads();
      }
    }
    cutHiB = cutLoB;
  }

  // ---- coalesced output dump: rows (score,x1,y1,x2,y2), zeros past nk ----
  __syncthreads();
  const int nkf = sh_nk;
  const float* kbf = (const float*)&kbox[0];
  for (int i = tid; i < TOPK * 5; i += 128) {
    int r = i / 5;
    int col = i - r * 5;
    float v = 0.0f;
    if (r < nkf) v = (col == 0) ? kscore[r] : kbf[r * 4 + (col - 1)];
    obase[i] = v;
  }
}

extern "C" void kernel_launch(void* const* d_in, const int* in_sizes, int n_in,
                              void* d_out, int out_size, void* d_ws, size_t ws_size,
                              hipStream_t stream) {
  const float* loc    = (const float*)d_in[0];
  const float* conf   = (const float*)d_in[1];
  const float* priors = (const float*)d_in[2];
  float* out = (float*)d_out;
  float4* wsbox = (float4*)d_ws;      // batch*3000*16 B = 12.3 MB

  const int batch = in_sizes[0] / (NPRI * 4);
  hipLaunchKernelGGL(decode_kernel, dim3(batch), dim3(256), 0, stream,
                     loc, priors, wsbox, out);
  hipLaunchKernelGGL(ssd_nms_kernel, dim3(batch * 20), dim3(128), 0, stream,
                     conf, wsbox, out, batch);
}